// Round 14
// baseline (314.091 us; speedup 1.0000x reference)
//
#include <hip/hip_runtime.h>
#include <math.h>
#include <stdint.h>

#define ND_ROWS 16384
#define DDIM    256
#define KCODES  8192
#define NSEG16  256        // 32-code segments (16x16 argmin)
#define NRG     8          // row groups (XCD-affine), 2048 rows each

typedef _Float16 f16x4 __attribute__((ext_vector_type(4)));
typedef _Float16 f16x8 __attribute__((ext_vector_type(8)));
typedef float    f32x4v __attribute__((ext_vector_type(4)));
typedef float    f32x16 __attribute__((ext_vector_type(16)));

// R24: the last untested occupancy cell - 8 waves/SIMD via 16x16x32 MFMA.
// Conservation law (R14/R15/R23): waves x per-wave-duty = 44% at 4w and 2w;
// per-wave stall shrinks with fewer waves => shared-resource contention, but
// no counter-visible pipe saturated. 8 waves/SIMD is unreachable with 32x32
// (acc[2][2] = 64 AGPR alone = the whole 8-wave budget). 16x16x32_f16:
// acc[2rt][2ct] = 16 AGPR; inner liveness ~56 regs; launch_bounds(512,8)
// forces <=64 -> 32 waves/CU (4 blocks x 8 waves, 4 x 32KB LDS = 128KB).
// A/B lane mapping (m=l&15, k=(l>>4)*8+j) mirrors the validated 32x32
// family; C/D col=lane&15,row=(lane>>4)*4+reg (m89). Slab: 32 codes as
// [ct(2)][tt(16)] 1KB chunks, lane slot l = (code c16, octet 4tt+l4) ->
// wave-contiguous conflict-free reads at compile-time imm offsets.
// Gates: VGPR=64, WRITE ~40MB (no spill). Break: util 55-75%. Hold: 44%
// at 3rd occupancy -> law structural -> revert R23 and stop.
// ---------------------------------------------------------------------------
// ws layout (bytes):
//   minpair [0,        131072)   u64[16384]  (init by prep)
//   counts  [131072,   163840)   int[8192]   (init by prep)
//   parts   [163840,   196608)   de[4096] | dq[4096]
//   neF     [196608,   229376)   float[8192] = ||e||^2
//   Xp      [229376,   17006592) x as MFMA B-operand fragments, 16.8 MB:
//            per 32-row block rb (32 KB): hi q=0..15 then lo q=0..15; unit
//            (rb,q) = 1 KB; 16B chunk index within unit = (kg<<5)|rl holding
//            halves k = q*16 + kg*8 .. +8 of row rl.
//   Bp      [17006592, 25395200) 8192 x 512 f16 = [-2e_hi(256) | -2e_lo(256)]
// ---------------------------------------------------------------------------

__device__ __attribute__((always_inline)) inline void load_lds16(const void* g, void* l) {
    __builtin_amdgcn_global_load_lds((const __attribute__((address_space(1))) void*)g,
                                     (__attribute__((address_space(3))) void*)l, 16, 0, 0);
}

// Blocks 0..511: x-transpose blocks (one rb = 32 rows each; LDS-staged,
// coalesced global I/O). Blocks 512..2559: emb wave-per-row.
__global__ __launch_bounds__(256) void prep_kernel(const float* __restrict__ x,
                                                   const float* __restrict__ emb,
                                                   _Float16* __restrict__ Xp,
                                                   _Float16* __restrict__ Bp,
                                                   float* __restrict__ neF,
                                                   unsigned long long* __restrict__ minpair,
                                                   int* __restrict__ counts) {
    __shared__ __align__(16) _Float16 S[16384];   // 32 KB staging (x-blocks)
    const int bid = blockIdx.x;
    const int tid = threadIdx.x;

    if (bid < 512) {
        // ---- x part: rb = bid, rows rb*32 .. +32 ----
        const int rb = bid;
        const float4* src = (const float4*)(x + (size_t)rb * 32 * DDIM); // 2048 float4
        #pragma unroll
        for (int i = 0; i < 8; ++i) {
            int g = i * 256 + tid;           // float4 index within the rb block
            float4 v = src[g];
            int rl = g >> 6;                 // row 0..31
            int k0 = (g & 63) << 2;          // k = k0 .. k0+3
            f16x4 hi, lo;
            hi[0] = (_Float16)v.x; lo[0] = (_Float16)(v.x - (float)hi[0]);
            hi[1] = (_Float16)v.y; lo[1] = (_Float16)(v.y - (float)hi[1]);
            hi[2] = (_Float16)v.z; lo[2] = (_Float16)(v.z - (float)hi[2]);
            hi[3] = (_Float16)v.w; lo[3] = (_Float16)(v.w - (float)hi[3]);
            // fragment offset (f16 units): q*512 + kg*256 + rl*8 + j0*4
            int off = ((k0 >> 4) << 9) + (((k0 >> 3) & 1) << 8)
                    + (rl << 3) + (((k0 >> 2) & 1) << 2);
            *(f16x4*)(S + off)        = hi;      // hi half [0, 8192)
            *(f16x4*)(S + off + 8192) = lo;      // lo half [8192, 16384)
        }
        if (tid < 32) minpair[rb * 32 + tid] = 0xFFFFFFFFFFFFFFFFull;
        __syncthreads();
        // LDS layout == output layout: straight coalesced copy (32 KB)
        float4* dst = (float4*)(Xp + (size_t)rb * 16384);
        const float4* sls = (const float4*)S;
        #pragma unroll
        for (int i = 0; i < 8; ++i) {
            int g = i * 256 + tid;
            dst[g] = sls[g];
        }
    } else {
        // ---- emb part: wave per codebook row ----
        int wave = ((bid - 512) << 2) + (tid >> 6);   // 0..8191
        int lane = tid & 63;
        int r    = wave;
        const float* src = emb + (size_t)r * DDIM;
        float4 v = ((const float4*)src)[lane];
        float s = v.x*v.x + v.y*v.y + v.z*v.z + v.w*v.w;  // ||e||^2 of original e
        #pragma unroll
        for (int m = 32; m; m >>= 1) s += __shfl_xor(s, m, 64);
        float4 t;                                         // fold the -2 in
        t.x = -2.0f * v.x; t.y = -2.0f * v.y; t.z = -2.0f * v.z; t.w = -2.0f * v.w;
        f16x4 hi, lo;
        hi[0] = (_Float16)t.x; lo[0] = (_Float16)(t.x - (float)hi[0]);
        hi[1] = (_Float16)t.y; lo[1] = (_Float16)(t.y - (float)hi[1]);
        hi[2] = (_Float16)t.z; lo[2] = (_Float16)(t.z - (float)hi[2]);
        hi[3] = (_Float16)t.w; lo[3] = (_Float16)(t.w - (float)hi[3]);
        _Float16* dst = Bp + (size_t)r * 512;
        *(f16x4*)(dst + lane * 4)       = hi;
        *(f16x4*)(dst + 256 + lane * 4) = lo;
        if (lane == 0) {
            neF[r] = s;
            counts[r] = 0;
        }
    }
}

// Barrier-free argmin GEMM, codes-as-M, mfma_f32_16x16x32_f16.
// 8 waves/SIMD target. Block = (rg, seg of 32 codes). Per wave: 256 rows
// (8 rb-blocks), per pass 32 rows x 32 codes via acc[2rt][2ct] (16 AGPR).
// Per t (K=32 window): 4 LDS A-reads + 4 global B-reads + 12 MFMA.
#define MFMA16x16(A, B, C) __builtin_amdgcn_mfma_f32_16x16x32_f16(A, B, C, 0, 0, 0)

__global__ __launch_bounds__(512, 8) void argmin_seg(
    const _Float16* __restrict__ Xp, const _Float16* __restrict__ Bp,
    const float* __restrict__ neF, unsigned long long* __restrict__ minpair) {
    __shared__ __align__(16) _Float16 Cs[16384];   // 32 KB

    const int tid  = threadIdx.x;
    const int lane = tid & 63;
    const int w    = tid >> 6;     // 0..7
    const int c16  = lane & 15;    // code-in-tile / x-row-in-tile
    const int l4   = lane >> 4;    // 0..3 (k-octet group)

    const int rg      = blockIdx.x & 7;
    const int seg     = blockIdx.x >> 3;      // 0..255
    const int rowBase = rg * 2048;
    const int code0   = seg * 32;

    // stage slab: chunk j (1 KB, linear dest): ct = j>>4, tt = j&15.
    // lane l slot holds code = code0 + ct*16 + (l&15), octet = 4*tt + (l>>4)
    // (octets 0..31 = hi dims, 32..63 = lo dims; tt*4 runs straight through).
    #pragma unroll
    for (int i = 0; i < 4; ++i) {
        int j    = w * 4 + i;
        int code = code0 + ((j >> 4) << 4) + c16;
        int oct  = ((j & 15) << 2) | l4;
        load_lds16((const char*)Bp + ((size_t)code << 10) + (oct << 4),
                   (char*)Cs + (j << 10));
    }
    __syncthreads();   // the only barrier

    // A-read base: wave-contiguous 1 KB per read, compile-time imm offsets.
    const char* ca = (const char*)Cs + (lane << 4);
    const int rbBase = (rowBase >> 5) + w * 8;   // 8 rb-blocks per wave

    #pragma unroll 1
    for (int p = 0; p < 8; ++p) {
        const int rb = rbBase + p;
        // B (X) lane address: row = rt*16 + c16 of rb; k-octet l4 of window t.
        // byte = t*2048 + l4*512 + (rt*16 + c16)*16 (+16384 for lo half).
        const char* xb = (const char*)Xp + (size_t)rb * 32768
                       + (l4 << 9) + (c16 << 4);

        f32x4v a00, a01, a10, a11;   // acc[rt][ct], 16 AGPR total
        #pragma unroll
        for (int i = 0; i < 4; ++i) { a00[i] = 0.0f; a01[i] = 0.0f;
                                      a10[i] = 0.0f; a11[i] = 0.0f; }

        #pragma unroll 2
        for (int t = 0; t < 8; ++t) {
            f16x8 xh0 = *(const f16x8*)(xb + t * 2048);
            f16x8 xh1 = *(const f16x8*)(xb + t * 2048 + 256);
            f16x8 xl0 = *(const f16x8*)(xb + 16384 + t * 2048);
            f16x8 xl1 = *(const f16x8*)(xb + 16384 + t * 2048 + 256);
            f16x8 ch0 = *(const f16x8*)(ca + t * 1024);             // ct0 hi
            f16x8 ch1 = *(const f16x8*)(ca + 16384 + t * 1024);     // ct1 hi
            a00 = MFMA16x16(ch0, xh0, a00);
            a01 = MFMA16x16(ch1, xh0, a01);
            a10 = MFMA16x16(ch0, xh1, a10);
            a11 = MFMA16x16(ch1, xh1, a11);
            a00 = MFMA16x16(ch0, xl0, a00);
            a01 = MFMA16x16(ch1, xl0, a01);
            a10 = MFMA16x16(ch0, xl1, a10);
            a11 = MFMA16x16(ch1, xl1, a11);
            f16x8 cl0 = *(const f16x8*)(ca + 8192 + t * 1024);      // ct0 lo
            f16x8 cl1 = *(const f16x8*)(ca + 24576 + t * 1024);     // ct1 lo
            a00 = MFMA16x16(cl0, xh0, a00);
            a01 = MFMA16x16(cl1, xh0, a01);
            a10 = MFMA16x16(cl0, xh1, a10);
            a11 = MFMA16x16(cl1, xh1, a11);
        }

        __builtin_amdgcn_sched_barrier(0);   // keep epilogue out of K-loop

        // epilogue: lane holds codes code0 + ct*16 + l4*4 + r for x-row c16.
        // Within-lane iteration (ct asc, r asc) => ids ascending; strict <
        // keeps first. Cross-lane: butterfly over l^16, l^32 w/ explicit tie.
        f32x4v ne0 = *(const f32x4v*)(neF + code0 + (l4 << 2));
        f32x4v ne1 = *(const f32x4v*)(neF + code0 + 16 + (l4 << 2));
        #pragma unroll
        for (int rt = 0; rt < 2; ++rt) {
            f32x4v d0 = rt ? a10 : a00;
            f32x4v d1 = rt ? a11 : a01;
            float best = 3.402823466e+38f;
            int   bi   = 0;
            #pragma unroll
            for (int r = 0; r < 4; ++r) {
                float d  = d0[r] + ne0[r];
                int   id = code0 + (l4 << 2) + r;
                if (d < best) { best = d; bi = id; }
            }
            #pragma unroll
            for (int r = 0; r < 4; ++r) {
                float d  = d1[r] + ne1[r];
                int   id = code0 + 16 + (l4 << 2) + r;
                if (d < best) { best = d; bi = id; }
            }
            float ov = __shfl_xor(best, 16, 64);
            int   oi = __shfl_xor(bi, 16, 64);
            if (ov < best || (ov == best && oi < bi)) { best = ov; bi = oi; }
            ov = __shfl_xor(best, 32, 64);
            oi = __shfl_xor(bi, 32, 64);
            if (ov < best || (ov == best && oi < bi)) { best = ov; bi = oi; }
            if (lane < 16) {
                int row = rb * 32 + rt * 16 + c16;
                unsigned u = __float_as_uint(best);
                u = (u & 0x80000000u) ? ~u : (u | 0x80000000u);   // total-order map
                atomicMin(&minpair[row],
                          (((unsigned long long)u) << 32) | (unsigned)bi);
            }
        }
    }
}

// decode packed min, gather codebook row, write quantized_sg + float index,
// histogram atomic + per-block SSE partials.
__global__ __launch_bounds__(256) void finalize_kernel(
    const float* __restrict__ x, const float* __restrict__ emb,
    const unsigned long long* __restrict__ minpair,
    float* __restrict__ out_q, float* __restrict__ out_idx,
    int* __restrict__ counts, float* __restrict__ parts) {
    __shared__ float rde[4], rdq[4];
    int wv   = threadIdx.x >> 6;
    int row  = (blockIdx.x << 2) + wv;
    int lane = threadIdx.x & 63;

    int bi = (int)(minpair[row] & 0xFFFFFFFFull);

    float4 xv = ((const float4*)(x   + (size_t)row * DDIM))[lane];
    float4 ev = ((const float4*)(emb + (size_t)bi  * DDIM))[lane];
    float4 q;
    q.x = xv.x + (ev.x - xv.x);
    q.y = xv.y + (ev.y - xv.y);
    q.z = xv.z + (ev.z - xv.z);
    q.w = xv.w + (ev.w - xv.w);
    ((float4*)(out_q + (size_t)row * DDIM))[lane] = q;

    float de = (ev.x - xv.x) * (ev.x - xv.x) + (ev.y - xv.y) * (ev.y - xv.y)
             + (ev.z - xv.z) * (ev.z - xv.z) + (ev.w - xv.w) * (ev.w - xv.w);
    float dq = (q.x - ev.x) * (q.x - ev.x) + (q.y - ev.y) * (q.y - ev.y)
             + (q.z - ev.z) * (q.z - ev.z) + (q.w - ev.w) * (q.w - ev.w);
    #pragma unroll
    for (int m = 32; m; m >>= 1) {
        de += __shfl_xor(de, m, 64);
        dq += __shfl_xor(dq, m, 64);
    }
    if (lane == 0) {
        out_idx[row] = (float)bi;
        atomicAdd(&counts[bi], 1);
        rde[wv] = de; rdq[wv] = dq;
    }
    __syncthreads();
    if (threadIdx.x == 0) {
        parts[blockIdx.x]        = rde[0] + rde[1] + rde[2] + rde[3];
        parts[4096 + blockIdx.x] = rdq[0] + rdq[1] + rdq[2] + rdq[3];
    }
}

__global__ __launch_bounds__(256) void scalars_kernel(
    const int* __restrict__ counts, const float* __restrict__ parts,
    float* __restrict__ out_loss, float* __restrict__ out_perp) {
    __shared__ float red[256], rde[256], rdq[256];
    float local = 0.0f, de = 0.0f, dq = 0.0f;
    for (int k = threadIdx.x; k < KCODES; k += 256) {
        float p = (float)counts[k] * (1.0f / (float)ND_ROWS);
        local += p * logf(p + 1e-10f);
    }
    for (int k = threadIdx.x; k < 4096; k += 256) {
        de += parts[k];
        dq += parts[4096 + k];
    }
    red[threadIdx.x] = local; rde[threadIdx.x] = de; rdq[threadIdx.x] = dq;
    __syncthreads();
    for (int s = 128; s; s >>= 1) {
        if (threadIdx.x < s) {
            red[threadIdx.x] += red[threadIdx.x + s];
            rde[threadIdx.x] += rde[threadIdx.x + s];
            rdq[threadIdx.x] += rdq[threadIdx.x + s];
        }
        __syncthreads();
    }
    if (threadIdx.x == 0) {
        *out_perp = expf(-red[0]);
        float invn = 1.0f / (float)(ND_ROWS * DDIM);
        *out_loss = rdq[0] * invn + 0.25f * (rde[0] * invn);
    }
}

extern "C" void kernel_launch(void* const* d_in, const int* in_sizes, int n_in,
                              void* d_out, int out_size, void* d_ws, size_t ws_size,
                              hipStream_t stream) {
    const float* x   = (const float*)d_in[0];
    const float* emb = (const float*)d_in[1];

    char* ws = (char*)d_ws;
    unsigned long long* minpair = (unsigned long long*)ws;         // 128 KB
    int*      counts = (int*)(ws + 131072);                        // 32 KB
    float*    parts  = (float*)(ws + 163840);                      // 32 KB
    float*    neF    = (float*)(ws + 196608);                      // 32 KB
    _Float16* Xp     = (_Float16*)(ws + 229376);                   // 16.8 MB
    _Float16* Bp     = (_Float16*)(ws + 17006592);                 // 8.4 MB

    float* out_q    = (float*)d_out;
    float* out_idx  = out_q + (size_t)ND_ROWS * DDIM;
    float* out_loss = out_idx + ND_ROWS;
    float* out_perp = out_loss + 1;

    prep_kernel<<<512 + KCODES / 4, 256, 0, stream>>>(x, emb, Xp, Bp, neF,
                                                      minpair, counts);
    argmin_seg<<<NRG * NSEG16, 512, 0, stream>>>(Xp, Bp, neF, minpair);
    finalize_kernel<<<ND_ROWS / 4, 256, 0, stream>>>(x, emb, minpair,
                                                     out_q, out_idx, counts, parts);
    scalars_kernel<<<1, 256, 0, stream>>>(counts, parts, out_loss, out_perp);
}

// Round 15
// 299.106 us; speedup vs baseline: 1.0501x; 1.0501x over previous
//
#include <hip/hip_runtime.h>
#include <math.h>
#include <stdint.h>

#define ND_ROWS 16384
#define DDIM    256
#define KCODES  8192
#define NSEG    128        // 64-code segments
#define NRG     8          // row groups (XCD-affine), 2048 rows each

typedef _Float16 f16x4 __attribute__((ext_vector_type(4)));
typedef _Float16 f16x8 __attribute__((ext_vector_type(8)));
typedef float    f32x4v __attribute__((ext_vector_type(4)));
typedef float    f32x16 __attribute__((ext_vector_type(16)));

// R25 = FINAL: revert to R23 (session best, 300.2 us total; argmin 215.5).
// Conservation law closed at 3 occupancies (R14 4w x 11% = R23 2w x 22% =
// R24 8w x 5.5% ~= 44-46% MfmaUtil): the argmin limiter scales with MFMA
// work itself (operand-delivery cost ~1.25x MFMA busy, invisible to
// capturable counters); no source-level lever moved it across 6 structures.
// Kernel kept: wide 128-row JIT tile (acc[4][2], 128 AGPR, no spill),
// transposed conflict-free code slab, XCD-affine rg, setprio on clusters,
// LDS-staged coalesced prep, memset-free init, separate scalars (no fences).
// ---------------------------------------------------------------------------
// ws layout (bytes):
//   minpair [0,        131072)   u64[16384]  (init by prep)
//   counts  [131072,   163840)   int[8192]   (init by prep)
//   parts   [163840,   196608)   de[4096] | dq[4096]
//   neF     [196608,   229376)   float[8192] = ||e||^2
//   Xp      [229376,   17006592) x as MFMA B-operand fragments, 16.8 MB:
//            per 32-row block rb (32 KB): hi q=0..15 then lo q=0..15; unit
//            (rb,q) = 1 KB; 16B chunk index within unit = (kg<<5)|rl holding
//            halves k = q*16 + kg*8 .. +8 of row rl.
//   Bp      [17006592, 25395200) 8192 x 512 f16 = [-2e_hi(256) | -2e_lo(256)]
// ---------------------------------------------------------------------------

__device__ __attribute__((always_inline)) inline void load_lds16(const void* g, void* l) {
    __builtin_amdgcn_global_load_lds((const __attribute__((address_space(1))) void*)g,
                                     (__attribute__((address_space(3))) void*)l, 16, 0, 0);
}

// Blocks 0..511: x-transpose blocks (one rb = 32 rows each; LDS-staged,
// coalesced global I/O). Blocks 512..2559: emb wave-per-row.
__global__ __launch_bounds__(256) void prep_kernel(const float* __restrict__ x,
                                                   const float* __restrict__ emb,
                                                   _Float16* __restrict__ Xp,
                                                   _Float16* __restrict__ Bp,
                                                   float* __restrict__ neF,
                                                   unsigned long long* __restrict__ minpair,
                                                   int* __restrict__ counts) {
    __shared__ __align__(16) _Float16 S[16384];   // 32 KB staging (x-blocks)
    const int bid = blockIdx.x;
    const int tid = threadIdx.x;

    if (bid < 512) {
        // ---- x part: rb = bid, rows rb*32 .. +32 ----
        const int rb = bid;
        const float4* src = (const float4*)(x + (size_t)rb * 32 * DDIM); // 2048 float4
        #pragma unroll
        for (int i = 0; i < 8; ++i) {
            int g = i * 256 + tid;           // float4 index within the rb block
            float4 v = src[g];
            int rl = g >> 6;                 // row 0..31
            int k0 = (g & 63) << 2;          // k = k0 .. k0+3
            f16x4 hi, lo;
            hi[0] = (_Float16)v.x; lo[0] = (_Float16)(v.x - (float)hi[0]);
            hi[1] = (_Float16)v.y; lo[1] = (_Float16)(v.y - (float)hi[1]);
            hi[2] = (_Float16)v.z; lo[2] = (_Float16)(v.z - (float)hi[2]);
            hi[3] = (_Float16)v.w; lo[3] = (_Float16)(v.w - (float)hi[3]);
            // fragment offset (f16 units): q*512 + kg*256 + rl*8 + j0*4
            int off = ((k0 >> 4) << 9) + (((k0 >> 3) & 1) << 8)
                    + (rl << 3) + (((k0 >> 2) & 1) << 2);
            *(f16x4*)(S + off)        = hi;      // hi half [0, 8192)
            *(f16x4*)(S + off + 8192) = lo;      // lo half [8192, 16384)
        }
        if (tid < 32) minpair[rb * 32 + tid] = 0xFFFFFFFFFFFFFFFFull;
        __syncthreads();
        // LDS layout == output layout: straight coalesced copy (32 KB)
        float4* dst = (float4*)(Xp + (size_t)rb * 16384);
        const float4* sls = (const float4*)S;
        #pragma unroll
        for (int i = 0; i < 8; ++i) {
            int g = i * 256 + tid;
            dst[g] = sls[g];
        }
    } else {
        // ---- emb part: wave per codebook row ----
        int wave = ((bid - 512) << 2) + (tid >> 6);   // 0..8191
        int lane = tid & 63;
        int r    = wave;
        const float* src = emb + (size_t)r * DDIM;
        float4 v = ((const float4*)src)[lane];
        float s = v.x*v.x + v.y*v.y + v.z*v.z + v.w*v.w;  // ||e||^2 of original e
        #pragma unroll
        for (int m = 32; m; m >>= 1) s += __shfl_xor(s, m, 64);
        float4 t;                                         // fold the -2 in
        t.x = -2.0f * v.x; t.y = -2.0f * v.y; t.z = -2.0f * v.z; t.w = -2.0f * v.w;
        f16x4 hi, lo;
        hi[0] = (_Float16)t.x; lo[0] = (_Float16)(t.x - (float)hi[0]);
        hi[1] = (_Float16)t.y; lo[1] = (_Float16)(t.y - (float)hi[1]);
        hi[2] = (_Float16)t.z; lo[2] = (_Float16)(t.z - (float)hi[2]);
        hi[3] = (_Float16)t.w; lo[3] = (_Float16)(t.w - (float)hi[3]);
        _Float16* dst = Bp + (size_t)r * 512;
        *(f16x4*)(dst + lane * 4)       = hi;
        *(f16x4*)(dst + 256 + lane * 4) = lo;
        if (lane == 0) {
            neF[r] = s;
            counts[r] = 0;
        }
    }
}

// Barrier-free argmin GEMM, codes-as-M, mfma_f32_32x32x16_f16.
// 4-chunk (128-row) JIT tile, acc[4][2] = 8 chains (128 AGPR), transposed
// conflict-free slab, launch_bounds(512,2). 24-MFMA clusters, setprio.
#define MFMA16(A, B, C) __builtin_amdgcn_mfma_f32_32x32x16_f16(A, B, C, 0, 0, 0)

__global__ __launch_bounds__(512, 2) void argmin_seg(
    const _Float16* __restrict__ Xp, const _Float16* __restrict__ Bp,
    const float* __restrict__ neF, unsigned long long* __restrict__ minpair) {
    __shared__ __align__(16) _Float16 Cs[64 * 512];   // 64 KB, nothing else

    const int tid  = threadIdx.x;
    const int lane = tid & 63;
    const int w    = tid >> 6;     // 0..7
    const int c32  = lane & 31;
    const int kg   = lane >> 5;

    const int rg      = blockIdx.x & 7;
    const int seg     = blockIdx.x >> 3;
    const int rowBase = rg * 2048;
    const int code0   = seg * 64;

    // stage code slab TRANSPOSED: LDS chunk j (1 KB, linear dest) holds
    // { slot 2*(j&31)+0 : codes 0..31 | slot 2*(j&31)+1 : codes 0..31 } of
    // code-half (j>>5). Lane l fetches global Bp[code0 + (j&32) + (l&31)]
    // slot (2*(j&31) + (l>>5)).  (16B-gather src; prologue-only, L2-hot.)
    #pragma unroll
    for (int i = 0; i < 8; ++i) {
        int j    = w * 8 + i;
        int code = code0 + (j & 32) + (lane & 31);
        int s    = ((j & 31) << 1) | (lane >> 5);
        load_lds16((const char*)Bp + ((size_t)code << 10) + (s << 4),
                   (char*)Cs + (j << 10));
    }
    __syncthreads();   // the only barrier

    // read base: lane offset c32*16 within a 512B slot-row, kg picks the
    // adjacent slot. Per q: 4 reads at compile-time offsets, each wave-
    // contiguous 1 KB -> conflict-free.
    const char* cpb = (const char*)Cs + (kg << 9) + (c32 << 4);

    const int wBase = rowBase + w * 256;   // 2 groups of 128 rows per wave
    #pragma unroll 1
    for (int c2 = 0; c2 < 2; ++c2) {
        const int rb0 = (wBase >> 5) + c2 * 4;
        const char* xb = (const char*)Xp + (size_t)rb0 * 32768 + lane * 16;
        f32x16 acc[4][2];   // [chunk][mt] - 8 independent MFMA chains, 128 AGPR
        #pragma unroll
        for (int ck = 0; ck < 4; ++ck)
            #pragma unroll
            for (int i = 0; i < 16; ++i) { acc[ck][0][i] = 0.0f; acc[ck][1][i] = 0.0f; }

        #pragma unroll 2
        for (int q = 0; q < 16; ++q) {
            f16x8 xh0 = *(const f16x8*)(xb + q * 1024);
            f16x8 xl0 = *(const f16x8*)(xb + 16384 + q * 1024);
            f16x8 xh1 = *(const f16x8*)(xb + 32768 + q * 1024);
            f16x8 xl1 = *(const f16x8*)(xb + 49152 + q * 1024);
            f16x8 xh2 = *(const f16x8*)(xb + 65536 + q * 1024);
            f16x8 xl2 = *(const f16x8*)(xb + 81920 + q * 1024);
            f16x8 xh3 = *(const f16x8*)(xb + 98304 + q * 1024);
            f16x8 xl3 = *(const f16x8*)(xb + 114688 + q * 1024);
            f16x8 ch0 = *(const f16x8*)(cpb + q * 1024);
            f16x8 cl0 = *(const f16x8*)(cpb + 16384 + q * 1024);
            f16x8 ch1 = *(const f16x8*)(cpb + 32768 + q * 1024);
            f16x8 cl1 = *(const f16x8*)(cpb + 49152 + q * 1024);
            // 24 MFMAs in 3 term-groups of 8; chain (ck,mt) reissues 8 slots
            // (256 cyc) apart. Products: ch*xh + ch*xl + cl*xh.
            __builtin_amdgcn_s_setprio(1);
            acc[0][0] = MFMA16(ch0, xh0, acc[0][0]);
            acc[0][1] = MFMA16(ch1, xh0, acc[0][1]);
            acc[1][0] = MFMA16(ch0, xh1, acc[1][0]);
            acc[1][1] = MFMA16(ch1, xh1, acc[1][1]);
            acc[2][0] = MFMA16(ch0, xh2, acc[2][0]);
            acc[2][1] = MFMA16(ch1, xh2, acc[2][1]);
            acc[3][0] = MFMA16(ch0, xh3, acc[3][0]);
            acc[3][1] = MFMA16(ch1, xh3, acc[3][1]);
            acc[0][0] = MFMA16(ch0, xl0, acc[0][0]);
            acc[0][1] = MFMA16(ch1, xl0, acc[0][1]);
            acc[1][0] = MFMA16(ch0, xl1, acc[1][0]);
            acc[1][1] = MFMA16(ch1, xl1, acc[1][1]);
            acc[2][0] = MFMA16(ch0, xl2, acc[2][0]);
            acc[2][1] = MFMA16(ch1, xl2, acc[2][1]);
            acc[3][0] = MFMA16(ch0, xl3, acc[3][0]);
            acc[3][1] = MFMA16(ch1, xl3, acc[3][1]);
            acc[0][0] = MFMA16(cl0, xh0, acc[0][0]);
            acc[0][1] = MFMA16(cl1, xh0, acc[0][1]);
            acc[1][0] = MFMA16(cl0, xh1, acc[1][0]);
            acc[1][1] = MFMA16(cl1, xh1, acc[1][1]);
            acc[2][0] = MFMA16(cl0, xh2, acc[2][0]);
            acc[2][1] = MFMA16(cl1, xh2, acc[2][1]);
            acc[3][0] = MFMA16(cl0, xh3, acc[3][0]);
            acc[3][1] = MFMA16(cl1, xh3, acc[3][1]);
            __builtin_amdgcn_s_setprio(0);
        }

        // epilogue: ne loaded here only (L1-hot after first iter). Code id of
        // acc[ck][mt][r] = code0 + mt*32 + 4*kg + (r&3) + 8*(r>>2); (mt,r)
        // ascending <=> id ascending; strict < => first(lowest-index)-wins.
        f32x4v ne4[2][4];
        #pragma unroll
        for (int mt = 0; mt < 2; ++mt)
            #pragma unroll
            for (int g2 = 0; g2 < 4; ++g2)
                ne4[mt][g2] = *(const f32x4v*)(neF + code0 + mt * 32 + g2 * 8 + 4 * kg);
        #pragma unroll
        for (int ck = 0; ck < 4; ++ck) {
            float best = 3.402823466e+38f;
            int   bi   = 0;
            #pragma unroll
            for (int mt = 0; mt < 2; ++mt)
                #pragma unroll
                for (int r = 0; r < 16; ++r) {
                    float d  = acc[ck][mt][r] + ne4[mt][r >> 2][r & 3];
                    int   id = code0 + mt * 32 + 4 * kg + ((r & 3) + 8 * (r >> 2));
                    if (d < best) { best = d; bi = id; }
                }
            float ov = __shfl_xor(best, 32, 64);
            int   oi = __shfl_xor(bi, 32, 64);
            if (ov < best || (ov == best && oi < bi)) { best = ov; bi = oi; }
            if (kg == 0) {
                int row = (rb0 + ck) * 32 + c32;
                unsigned u = __float_as_uint(best);
                u = (u & 0x80000000u) ? ~u : (u | 0x80000000u);   // total-order map
                atomicMin(&minpair[row],
                          (((unsigned long long)u) << 32) | (unsigned)bi);
            }
        }
    }
}

// decode packed min, gather codebook row, write quantized_sg + float index,
// histogram atomic + per-block SSE partials.
__global__ __launch_bounds__(256) void finalize_kernel(
    const float* __restrict__ x, const float* __restrict__ emb,
    const unsigned long long* __restrict__ minpair,
    float* __restrict__ out_q, float* __restrict__ out_idx,
    int* __restrict__ counts, float* __restrict__ parts) {
    __shared__ float rde[4], rdq[4];
    int wv   = threadIdx.x >> 6;
    int row  = (blockIdx.x << 2) + wv;
    int lane = threadIdx.x & 63;

    int bi = (int)(minpair[row] & 0xFFFFFFFFull);

    float4 xv = ((const float4*)(x   + (size_t)row * DDIM))[lane];
    float4 ev = ((const float4*)(emb + (size_t)bi  * DDIM))[lane];
    float4 q;
    q.x = xv.x + (ev.x - xv.x);
    q.y = xv.y + (ev.y - xv.y);
    q.z = xv.z + (ev.z - xv.z);
    q.w = xv.w + (ev.w - xv.w);
    ((float4*)(out_q + (size_t)row * DDIM))[lane] = q;

    float de = (ev.x - xv.x) * (ev.x - xv.x) + (ev.y - xv.y) * (ev.y - xv.y)
             + (ev.z - xv.z) * (ev.z - xv.z) + (ev.w - xv.w) * (ev.w - xv.w);
    float dq = (q.x - ev.x) * (q.x - ev.x) + (q.y - ev.y) * (q.y - ev.y)
             + (q.z - ev.z) * (q.z - ev.z) + (q.w - ev.w) * (q.w - ev.w);
    #pragma unroll
    for (int m = 32; m; m >>= 1) {
        de += __shfl_xor(de, m, 64);
        dq += __shfl_xor(dq, m, 64);
    }
    if (lane == 0) {
        out_idx[row] = (float)bi;
        atomicAdd(&counts[bi], 1);
        rde[wv] = de; rdq[wv] = dq;
    }
    __syncthreads();
    if (threadIdx.x == 0) {
        parts[blockIdx.x]        = rde[0] + rde[1] + rde[2] + rde[3];
        parts[4096 + blockIdx.x] = rdq[0] + rdq[1] + rdq[2] + rdq[3];
    }
}

__global__ __launch_bounds__(256) void scalars_kernel(
    const int* __restrict__ counts, const float* __restrict__ parts,
    float* __restrict__ out_loss, float* __restrict__ out_perp) {
    __shared__ float red[256], rde[256], rdq[256];
    float local = 0.0f, de = 0.0f, dq = 0.0f;
    for (int k = threadIdx.x; k < KCODES; k += 256) {
        float p = (float)counts[k] * (1.0f / (float)ND_ROWS);
        local += p * logf(p + 1e-10f);
    }
    for (int k = threadIdx.x; k < 4096; k += 256) {
        de += parts[k];
        dq += parts[4096 + k];
    }
    red[threadIdx.x] = local; rde[threadIdx.x] = de; rdq[threadIdx.x] = dq;
    __syncthreads();
    for (int s = 128; s; s >>= 1) {
        if (threadIdx.x < s) {
            red[threadIdx.x] += red[threadIdx.x + s];
            rde[threadIdx.x] += rde[threadIdx.x + s];
            rdq[threadIdx.x] += rdq[threadIdx.x + s];
        }
        __syncthreads();
    }
    if (threadIdx.x == 0) {
        *out_perp = expf(-red[0]);
        float invn = 1.0f / (float)(ND_ROWS * DDIM);
        *out_loss = rdq[0] * invn + 0.25f * (rde[0] * invn);
    }
}

extern "C" void kernel_launch(void* const* d_in, const int* in_sizes, int n_in,
                              void* d_out, int out_size, void* d_ws, size_t ws_size,
                              hipStream_t stream) {
    const float* x   = (const float*)d_in[0];
    const float* emb = (const float*)d_in[1];

    char* ws = (char*)d_ws;
    unsigned long long* minpair = (unsigned long long*)ws;         // 128 KB
    int*      counts = (int*)(ws + 131072);                        // 32 KB
    float*    parts  = (float*)(ws + 163840);                      // 32 KB
    float*    neF    = (float*)(ws + 196608);                      // 32 KB
    _Float16* Xp     = (_Float16*)(ws + 229376);                   // 16.8 MB
    _Float16* Bp     = (_Float16*)(ws + 17006592);                 // 8.4 MB

    float* out_q    = (float*)d_out;
    float* out_idx  = out_q + (size_t)ND_ROWS * DDIM;
    float* out_loss = out_idx + ND_ROWS;
    float* out_perp = out_loss + 1;

    prep_kernel<<<512 + KCODES / 4, 256, 0, stream>>>(x, emb, Xp, Bp, neF,
                                                      minpair, counts);
    argmin_seg<<<NRG * NSEG, 512, 0, stream>>>(Xp, Bp, neF, minpair);
    finalize_kernel<<<ND_ROWS / 4, 256, 0, stream>>>(x, emb, minpair,
                                                     out_q, out_idx, counts, parts);
    scalars_kernel<<<1, 256, 0, stream>>>(counts, parts, out_loss, out_perp);
}